// Round 1
// baseline (5799.533 us; speedup 1.0000x reference)
//
#include <hip/hip_runtime.h>
#include <hip/hip_bf16.h>

typedef __bf16 bf16_t;
typedef bf16_t bf16x8 __attribute__((ext_vector_type(8)));
typedef float f32x4 __attribute__((ext_vector_type(4)));

#define MFMA16(a, b, c) __builtin_amdgcn_mfma_f32_16x16x32_bf16(a, b, c, 0, 0, 0)

static constexpr int E_EDGE = 786432;
static constexpr int N_GRID = 262144;
static constexpr int DIM = 128;

// out[n*K + k] = (bf16) in[k*N + n]   (transpose KxN -> NxK, fp32 -> bf16)
__global__ void transpose_to_bf16(const float* __restrict__ in, bf16_t* __restrict__ out,
                                  int K, int N) {
    int idx = blockIdx.x * 256 + threadIdx.x;
    if (idx < K * N) {
        int n = idx / K;
        int k = idx - n * K;
        out[idx] = (bf16_t)in[k * N + n];
    }
}

// ---------------- Edge MLP: cat(efeat, mesh[src], grid[dst]) [384] -> 256 (SiLU) -> 128 (LN)
// then atomicAdd rows into agg[dst].  64 edges per block, 512 threads (8 waves).
__global__ __launch_bounds__(512, 4) void edge_mlp_kernel(
    const float* __restrict__ efeat, const float* __restrict__ gridf,
    const float* __restrict__ meshf, const int* __restrict__ src_idx,
    const int* __restrict__ dst_idx,
    const bf16_t* __restrict__ W1T,  // [256][384]
    const float* __restrict__ b1,
    const bf16_t* __restrict__ W2T,  // [128][256]
    const float* __restrict__ b2,
    const float* __restrict__ g, const float* __restrict__ beta,
    float* __restrict__ agg) {
    __shared__ bf16_t A_tile[64 * 40];    // 5120 B  (64 rows x 32 k, pad to 40)
    __shared__ bf16_t B_tile[256 * 40];   // 20480 B (256 n x 32 k, pad to 40)
    __shared__ bf16_t h_lds[64 * 264];    // 33792 B (64 x 256, pad to 264)
    __shared__ int sidx[64], didx[64];
    float* out_lds = (float*)h_lds;       // aliases h_lds: [64][132] f32 = 33792 B

    const int tid = threadIdx.x;
    const int wave = tid >> 6, lane = tid & 63;
    const int l15 = lane & 15, lg = lane >> 4;
    const int e0 = blockIdx.x * 64;

    if (tid < 64) {
        sidx[tid] = src_idx[e0 + tid];
        didx[tid] = dst_idx[e0 + tid];
    }
    __syncthreads();

    // ---- GEMM1: [64,384] x [384,256] ----
    const int n0 = wave * 32;
    f32x4 acc[4][2] = {};
    const int arow = tid >> 3, acq = (tid & 7) * 4;  // A staging: row, col4
    const int brow = tid >> 1, bh = tid & 1;         // B staging: n row, 16-elem half

    for (int kk = 0; kk < 12; ++kk) {
        const int k0 = kk * 32;
        // stage A (gather + fp32->bf16)
        {
            const int kcol = k0 + acq;
            const float* srcp;
            if (kcol < 128)
                srcp = efeat + (size_t)(e0 + arow) * 128 + kcol;
            else if (kcol < 256)
                srcp = meshf + (size_t)sidx[arow] * 128 + (kcol - 128);
            else
                srcp = gridf + (size_t)didx[arow] * 128 + (kcol - 256);
            float4 v = *reinterpret_cast<const float4*>(srcp);
            bf16_t* dp = &A_tile[arow * 40 + acq];
            dp[0] = (bf16_t)v.x; dp[1] = (bf16_t)v.y; dp[2] = (bf16_t)v.z; dp[3] = (bf16_t)v.w;
        }
        // stage B from W1T
        {
            const uint4* sp = reinterpret_cast<const uint4*>(W1T + (size_t)brow * 384 + k0 + bh * 16);
            uint4 v0 = sp[0], v1 = sp[1];
            uint4* dp = reinterpret_cast<uint4*>(&B_tile[brow * 40 + bh * 16]);
            dp[0] = v0; dp[1] = v1;
        }
        __syncthreads();
        bf16x8 a[4], b[2];
#pragma unroll
        for (int mt = 0; mt < 4; ++mt)
            a[mt] = *reinterpret_cast<const bf16x8*>(&A_tile[(mt * 16 + l15) * 40 + lg * 8]);
#pragma unroll
        for (int nt = 0; nt < 2; ++nt)
            b[nt] = *reinterpret_cast<const bf16x8*>(&B_tile[(n0 + nt * 16 + l15) * 40 + lg * 8]);
#pragma unroll
        for (int mt = 0; mt < 4; ++mt)
#pragma unroll
            for (int nt = 0; nt < 2; ++nt)
                acc[mt][nt] = MFMA16(a[mt], b[nt], acc[mt][nt]);
        __syncthreads();
    }

    // bias + SiLU -> h (bf16) to LDS
#pragma unroll
    for (int mt = 0; mt < 4; ++mt)
#pragma unroll
        for (int nt = 0; nt < 2; ++nt) {
            const int col = n0 + nt * 16 + l15;
            const float bb = b1[col];
#pragma unroll
            for (int i = 0; i < 4; ++i) {
                const int row = mt * 16 + lg * 4 + i;
                const float x = acc[mt][nt][i] + bb;
                const float s = x / (1.f + __expf(-x));
                h_lds[row * 264 + col] = (bf16_t)s;
            }
        }
    __syncthreads();

    // ---- GEMM2: [64,256] x [256,128] ----
    f32x4 acc2[4] = {};
    const int n2 = wave * 16;
    const int b2row = tid >> 2, b2q = tid & 3;
    for (int kk = 0; kk < 8; ++kk) {
        const int k0 = kk * 32;
        {
            const uint4* sp = reinterpret_cast<const uint4*>(W2T + (size_t)b2row * 256 + k0 + b2q * 8);
            *reinterpret_cast<uint4*>(&B_tile[b2row * 40 + b2q * 8]) = *sp;
        }
        __syncthreads();
        bf16x8 a[4], b;
#pragma unroll
        for (int mt = 0; mt < 4; ++mt)
            a[mt] = *reinterpret_cast<const bf16x8*>(&h_lds[(mt * 16 + l15) * 264 + k0 + lg * 8]);
        b = *reinterpret_cast<const bf16x8*>(&B_tile[(n2 + l15) * 40 + lg * 8]);
#pragma unroll
        for (int mt = 0; mt < 4; ++mt)
            acc2[mt] = MFMA16(a[mt], b, acc2[mt]);
        __syncthreads();
    }

    // epilogue: bias -> out_lds (f32), LN per row, atomic scatter to agg[dst]
#pragma unroll
    for (int mt = 0; mt < 4; ++mt) {
        const int col = n2 + l15;
        const float bb = b2[col];
#pragma unroll
        for (int i = 0; i < 4; ++i) {
            const int row = mt * 16 + lg * 4 + i;
            out_lds[row * 132 + col] = acc2[mt][i] + bb;
        }
    }
    __syncthreads();
    {
        const int row = tid >> 3, j = tid & 7;
        const float* rp = &out_lds[row * 132 + j * 16];
        float v[16];
        float s = 0.f, sq = 0.f;
#pragma unroll
        for (int c = 0; c < 16; ++c) {
            v[c] = rp[c];
            s += v[c];
            sq += v[c] * v[c];
        }
#pragma unroll
        for (int d = 1; d < 8; d <<= 1) {
            s += __shfl_xor(s, d);
            sq += __shfl_xor(sq, d);
        }
        const float mean = s * (1.f / 128.f);
        const float var = sq * (1.f / 128.f) - mean * mean;
        const float rstd = rsqrtf(var + 1e-5f);
        const int dst = didx[row];
        float* ap = agg + (size_t)dst * 128 + j * 16;
#pragma unroll
        for (int c = 0; c < 16; ++c) {
            const int col = j * 16 + c;
            const float y = (v[c] - mean) * rstd * g[col] + beta[col];
            atomicAdd(&ap[c], y);
        }
    }
}

// ---------------- Node MLP: cat(agg, grid_nfeat) [256] -> 256 (SiLU) -> 128 (LN) + residual
// 64 nodes per block, 512 threads. agg may alias out (row-local read-then-write).
__global__ __launch_bounds__(512, 4) void node_mlp_kernel(
    const float* __restrict__ agg, const float* __restrict__ gridf,
    const bf16_t* __restrict__ W1T,  // [256][256]
    const float* __restrict__ b1,
    const bf16_t* __restrict__ W2T,  // [128][256]
    const float* __restrict__ b2,
    const float* __restrict__ g, const float* __restrict__ beta,
    float* __restrict__ out) {
    __shared__ bf16_t A_tile[64 * 40];
    __shared__ bf16_t B_tile[256 * 40];
    __shared__ bf16_t h_lds[64 * 264];
    float* out_lds = (float*)h_lds;

    const int tid = threadIdx.x;
    const int wave = tid >> 6, lane = tid & 63;
    const int l15 = lane & 15, lg = lane >> 4;
    const int g0 = blockIdx.x * 64;

    const int n0 = wave * 32;
    f32x4 acc[4][2] = {};
    const int arow = tid >> 3, acq = (tid & 7) * 4;
    const int brow = tid >> 1, bh = tid & 1;

    for (int kk = 0; kk < 8; ++kk) {
        const int k0 = kk * 32;
        {
            const int kcol = k0 + acq;
            const float* srcp = (kcol < 128)
                                    ? agg + (size_t)(g0 + arow) * 128 + kcol
                                    : gridf + (size_t)(g0 + arow) * 128 + (kcol - 128);
            float4 v = *reinterpret_cast<const float4*>(srcp);
            bf16_t* dp = &A_tile[arow * 40 + acq];
            dp[0] = (bf16_t)v.x; dp[1] = (bf16_t)v.y; dp[2] = (bf16_t)v.z; dp[3] = (bf16_t)v.w;
        }
        {
            const uint4* sp = reinterpret_cast<const uint4*>(W1T + (size_t)brow * 256 + k0 + bh * 16);
            uint4 v0 = sp[0], v1 = sp[1];
            uint4* dp = reinterpret_cast<uint4*>(&B_tile[brow * 40 + bh * 16]);
            dp[0] = v0; dp[1] = v1;
        }
        __syncthreads();
        bf16x8 a[4], b[2];
#pragma unroll
        for (int mt = 0; mt < 4; ++mt)
            a[mt] = *reinterpret_cast<const bf16x8*>(&A_tile[(mt * 16 + l15) * 40 + lg * 8]);
#pragma unroll
        for (int nt = 0; nt < 2; ++nt)
            b[nt] = *reinterpret_cast<const bf16x8*>(&B_tile[(n0 + nt * 16 + l15) * 40 + lg * 8]);
#pragma unroll
        for (int mt = 0; mt < 4; ++mt)
#pragma unroll
            for (int nt = 0; nt < 2; ++nt)
                acc[mt][nt] = MFMA16(a[mt], b[nt], acc[mt][nt]);
        __syncthreads();
    }

#pragma unroll
    for (int mt = 0; mt < 4; ++mt)
#pragma unroll
        for (int nt = 0; nt < 2; ++nt) {
            const int col = n0 + nt * 16 + l15;
            const float bb = b1[col];
#pragma unroll
            for (int i = 0; i < 4; ++i) {
                const int row = mt * 16 + lg * 4 + i;
                const float x = acc[mt][nt][i] + bb;
                const float s = x / (1.f + __expf(-x));
                h_lds[row * 264 + col] = (bf16_t)s;
            }
        }
    __syncthreads();

    f32x4 acc2[4] = {};
    const int n2 = wave * 16;
    const int b2row = tid >> 2, b2q = tid & 3;
    for (int kk = 0; kk < 8; ++kk) {
        const int k0 = kk * 32;
        {
            const uint4* sp = reinterpret_cast<const uint4*>(W2T + (size_t)b2row * 256 + k0 + b2q * 8);
            *reinterpret_cast<uint4*>(&B_tile[b2row * 40 + b2q * 8]) = *sp;
        }
        __syncthreads();
        bf16x8 a[4], b;
#pragma unroll
        for (int mt = 0; mt < 4; ++mt)
            a[mt] = *reinterpret_cast<const bf16x8*>(&h_lds[(mt * 16 + l15) * 264 + k0 + lg * 8]);
        b = *reinterpret_cast<const bf16x8*>(&B_tile[(n2 + l15) * 40 + lg * 8]);
#pragma unroll
        for (int mt = 0; mt < 4; ++mt)
            acc2[mt] = MFMA16(a[mt], b, acc2[mt]);
        __syncthreads();
    }

#pragma unroll
    for (int mt = 0; mt < 4; ++mt) {
        const int col = n2 + l15;
        const float bb = b2[col];
#pragma unroll
        for (int i = 0; i < 4; ++i) {
            const int row = mt * 16 + lg * 4 + i;
            out_lds[row * 132 + col] = acc2[mt][i] + bb;
        }
    }
    __syncthreads();
    {
        const int row = tid >> 3, j = tid & 7;
        const float* rp = &out_lds[row * 132 + j * 16];
        float v[16];
        float s = 0.f, sq = 0.f;
#pragma unroll
        for (int c = 0; c < 16; ++c) {
            v[c] = rp[c];
            s += v[c];
            sq += v[c] * v[c];
        }
#pragma unroll
        for (int d = 1; d < 8; d <<= 1) {
            s += __shfl_xor(s, d);
            sq += __shfl_xor(sq, d);
        }
        const float mean = s * (1.f / 128.f);
        const float var = sq * (1.f / 128.f) - mean * mean;
        const float rstd = rsqrtf(var + 1e-5f);
        const float* gp = gridf + (size_t)(g0 + row) * 128 + j * 16;
        float* op = out + (size_t)(g0 + row) * 128 + j * 16;
#pragma unroll
        for (int q = 0; q < 4; ++q) {
            float4 gv = *reinterpret_cast<const float4*>(gp + q * 4);
            float4 r;
            r.x = (v[q * 4 + 0] - mean) * rstd * g[j * 16 + q * 4 + 0] + beta[j * 16 + q * 4 + 0] + gv.x;
            r.y = (v[q * 4 + 1] - mean) * rstd * g[j * 16 + q * 4 + 1] + beta[j * 16 + q * 4 + 1] + gv.y;
            r.z = (v[q * 4 + 2] - mean) * rstd * g[j * 16 + q * 4 + 2] + beta[j * 16 + q * 4 + 2] + gv.z;
            r.w = (v[q * 4 + 3] - mean) * rstd * g[j * 16 + q * 4 + 3] + beta[j * 16 + q * 4 + 3] + gv.w;
            *reinterpret_cast<float4*>(op + q * 4) = r;
        }
    }
}

extern "C" void kernel_launch(void* const* d_in, const int* in_sizes, int n_in,
                              void* d_out, int out_size, void* d_ws, size_t ws_size,
                              hipStream_t stream) {
    const float* m2g = (const float*)d_in[0];
    const float* gridf = (const float*)d_in[1];
    const float* meshf = (const float*)d_in[2];
    const int* src_idx = (const int*)d_in[3];
    const int* dst_idx = (const int*)d_in[4];
    const float* eW1 = (const float*)d_in[5];
    const float* eb1 = (const float*)d_in[6];
    const float* eW2 = (const float*)d_in[7];
    const float* eb2 = (const float*)d_in[8];
    const float* eg = (const float*)d_in[9];
    const float* ebeta = (const float*)d_in[10];
    const float* nW1 = (const float*)d_in[11];
    const float* nb1 = (const float*)d_in[12];
    const float* nW2 = (const float*)d_in[13];
    const float* nb2 = (const float*)d_in[14];
    const float* ng = (const float*)d_in[15];
    const float* nbeta = (const float*)d_in[16];
    float* out = (float*)d_out;

    bf16_t* W1eT = (bf16_t*)d_ws;          // [256][384]
    bf16_t* W2eT = W1eT + 256 * 384;       // [128][256]
    bf16_t* W1nT = W2eT + 128 * 256;       // [256][256]
    bf16_t* W2nT = W1nT + 256 * 256;       // [128][256]

    // agg lives in d_out; zero it first (edge kernel atomically accumulates into it)
    hipMemsetAsync(d_out, 0, (size_t)N_GRID * DIM * sizeof(float), stream);

    transpose_to_bf16<<<(384 * 256 + 255) / 256, 256, 0, stream>>>(eW1, W1eT, 384, 256);
    transpose_to_bf16<<<(256 * 128 + 255) / 256, 256, 0, stream>>>(eW2, W2eT, 256, 128);
    transpose_to_bf16<<<(256 * 256 + 255) / 256, 256, 0, stream>>>(nW1, W1nT, 256, 256);
    transpose_to_bf16<<<(256 * 128 + 255) / 256, 256, 0, stream>>>(nW2, W2nT, 256, 128);

    edge_mlp_kernel<<<E_EDGE / 64, 512, 0, stream>>>(m2g, gridf, meshf, src_idx, dst_idx,
                                                     W1eT, eb1, W2eT, eb2, eg, ebeta, out);
    node_mlp_kernel<<<N_GRID / 64, 512, 0, stream>>>(out, gridf, W1nT, nb1, W2nT, nb2,
                                                     ng, nbeta, out);
}

// Round 2
// 979.170 us; speedup vs baseline: 5.9229x; 5.9229x over previous
//
#include <hip/hip_runtime.h>
#include <hip/hip_bf16.h>

typedef __bf16 bf16_t;
typedef bf16_t bf16x8 __attribute__((ext_vector_type(8)));
typedef float f32x4 __attribute__((ext_vector_type(4)));

#define MFMA16(a, b, c) __builtin_amdgcn_mfma_f32_16x16x32_bf16(a, b, c, 0, 0, 0)

static constexpr int E_EDGE = 786432;
static constexpr int N_GRID = 262144;
static constexpr int DIM = 128;

// out[n*K + k] = (bf16) in[k*N + n]   (transpose KxN -> NxK, fp32 -> bf16)
__global__ void transpose_to_bf16(const float* __restrict__ in, bf16_t* __restrict__ out,
                                  int K, int N) {
    int idx = blockIdx.x * 256 + threadIdx.x;
    if (idx < K * N) {
        int n = idx / K;
        int k = idx - n * K;
        out[idx] = (bf16_t)in[k * N + n];
    }
}

// ---------------- Edge MLP: cat(efeat, mesh[src], grid[dst]) [384] -> 256 (SiLU) -> 128 (LN)
// then coalesced atomicAdd rows into agg[dst].  64 edges per block, 512 threads (8 waves).
__global__ __launch_bounds__(512, 4) void edge_mlp_kernel(
    const float* __restrict__ efeat, const float* __restrict__ gridf,
    const float* __restrict__ meshf, const int* __restrict__ src_idx,
    const int* __restrict__ dst_idx,
    const bf16_t* __restrict__ W1T,  // [256][384]
    const float* __restrict__ b1,
    const bf16_t* __restrict__ W2T,  // [128][256]
    const float* __restrict__ b2,
    const float* __restrict__ g, const float* __restrict__ beta,
    float* __restrict__ agg) {
    __shared__ bf16_t A_tile[64 * 40];    // 5120 B
    __shared__ bf16_t B_tile[256 * 40];   // 20480 B
    __shared__ bf16_t h_lds[64 * 264];    // 33792 B
    __shared__ int sidx[64], didx[64];
    float* out_lds = (float*)h_lds;       // aliases h_lds: [64][132] f32

    const int tid = threadIdx.x;
    const int wave = tid >> 6, lane = tid & 63;
    const int l15 = lane & 15, lg = lane >> 4;
    const int e0 = blockIdx.x * 64;

    if (tid < 64) {
        sidx[tid] = src_idx[e0 + tid];
        didx[tid] = dst_idx[e0 + tid];
    }
    __syncthreads();

    // ---- GEMM1: [64,384] x [384,256], software-pipelined K staging ----
    const int n0 = wave * 32;
    f32x4 acc[4][2] = {};
    const int arow = tid >> 3, acq = (tid & 7) * 4;  // A staging: row, col4
    const int brow = tid >> 1, bh = tid & 1;         // B staging: n row, 16-elem half

    float4 aR;
    uint4 bR0, bR1;
#define LOAD_A1(kk)                                                              \
    {                                                                            \
        const int kcol = (kk) * 32 + acq;                                        \
        const float* srcp;                                                       \
        if (kcol < 128)                                                          \
            srcp = efeat + (size_t)(e0 + arow) * 128 + kcol;                     \
        else if (kcol < 256)                                                     \
            srcp = meshf + (size_t)sidx[arow] * 128 + (kcol - 128);              \
        else                                                                     \
            srcp = gridf + (size_t)didx[arow] * 128 + (kcol - 256);              \
        aR = *reinterpret_cast<const float4*>(srcp);                             \
    }
#define LOAD_B1(kk)                                                              \
    {                                                                            \
        const uint4* sp =                                                        \
            reinterpret_cast<const uint4*>(W1T + (size_t)brow * 384 + (kk) * 32 + bh * 16); \
        bR0 = sp[0];                                                             \
        bR1 = sp[1];                                                             \
    }

    LOAD_A1(0);
    LOAD_B1(0);
    for (int kk = 0; kk < 12; ++kk) {
        // write staged registers to LDS (packed 8B A write)
        {
            union { bf16_t h[4]; uint2 u; } pk;
            pk.h[0] = (bf16_t)aR.x; pk.h[1] = (bf16_t)aR.y;
            pk.h[2] = (bf16_t)aR.z; pk.h[3] = (bf16_t)aR.w;
            *reinterpret_cast<uint2*>(&A_tile[arow * 40 + acq]) = pk.u;
            uint4* dp = reinterpret_cast<uint4*>(&B_tile[brow * 40 + bh * 16]);
            dp[0] = bR0; dp[1] = bR1;
        }
        __syncthreads();
        if (kk < 11) {
            LOAD_A1(kk + 1);
            LOAD_B1(kk + 1);
        }
        bf16x8 a[4], b[2];
#pragma unroll
        for (int mt = 0; mt < 4; ++mt)
            a[mt] = *reinterpret_cast<const bf16x8*>(&A_tile[(mt * 16 + l15) * 40 + lg * 8]);
#pragma unroll
        for (int nt = 0; nt < 2; ++nt)
            b[nt] = *reinterpret_cast<const bf16x8*>(&B_tile[(n0 + nt * 16 + l15) * 40 + lg * 8]);
#pragma unroll
        for (int mt = 0; mt < 4; ++mt)
#pragma unroll
            for (int nt = 0; nt < 2; ++nt)
                acc[mt][nt] = MFMA16(a[mt], b[nt], acc[mt][nt]);
        __syncthreads();
    }

    // bias + SiLU -> h (bf16) to LDS
#pragma unroll
    for (int mt = 0; mt < 4; ++mt)
#pragma unroll
        for (int nt = 0; nt < 2; ++nt) {
            const int col = n0 + nt * 16 + l15;
            const float bb = b1[col];
#pragma unroll
            for (int i = 0; i < 4; ++i) {
                const int row = mt * 16 + lg * 4 + i;
                const float x = acc[mt][nt][i] + bb;
                const float s = x / (1.f + __expf(-x));
                h_lds[row * 264 + col] = (bf16_t)s;
            }
        }
    __syncthreads();

    // ---- GEMM2: [64,256] x [256,128], pipelined W2 staging ----
    f32x4 acc2[4] = {};
    const int n2 = wave * 16;
    const int b2row = tid >> 2, b2q = tid & 3;
    uint4 wR = *reinterpret_cast<const uint4*>(W2T + (size_t)b2row * 256 + b2q * 8);
    for (int kk = 0; kk < 8; ++kk) {
        *reinterpret_cast<uint4*>(&B_tile[b2row * 40 + b2q * 8]) = wR;
        __syncthreads();
        if (kk < 7)
            wR = *reinterpret_cast<const uint4*>(W2T + (size_t)b2row * 256 + (kk + 1) * 32 + b2q * 8);
        bf16x8 a[4], b;
#pragma unroll
        for (int mt = 0; mt < 4; ++mt)
            a[mt] = *reinterpret_cast<const bf16x8*>(&h_lds[(mt * 16 + l15) * 264 + kk * 32 + lg * 8]);
        b = *reinterpret_cast<const bf16x8*>(&B_tile[(n2 + l15) * 40 + lg * 8]);
#pragma unroll
        for (int mt = 0; mt < 4; ++mt)
            acc2[mt] = MFMA16(a[mt], b, acc2[mt]);
        __syncthreads();
    }

    // epilogue: bias -> out_lds (f32)
#pragma unroll
    for (int mt = 0; mt < 4; ++mt) {
        const int col = n2 + l15;
        const float bb = b2[col];
#pragma unroll
        for (int i = 0; i < 4; ++i) {
            const int row = mt * 16 + lg * 4 + i;
            out_lds[row * 132 + col] = acc2[mt][i] + bb;
        }
    }
    __syncthreads();
    // LN per row (8 threads/row), write y back in place
    {
        const int row = tid >> 3, j = tid & 7;
        float* rp = &out_lds[row * 132 + j * 16];
        float v[16];
        float s = 0.f, sq = 0.f;
#pragma unroll
        for (int c = 0; c < 16; ++c) {
            v[c] = rp[c];
            s += v[c];
            sq += v[c] * v[c];
        }
#pragma unroll
        for (int d = 1; d < 8; d <<= 1) {
            s += __shfl_xor(s, d);
            sq += __shfl_xor(sq, d);
        }
        const float mean = s * (1.f / 128.f);
        const float var = sq * (1.f / 128.f) - mean * mean;
        const float rstd = rsqrtf(var + 1e-5f);
#pragma unroll
        for (int c = 0; c < 16; ++c) {
            const int col = j * 16 + c;
            rp[c] = (v[c] - mean) * rstd * g[col] + beta[col];
        }
    }
    __syncthreads();
    // coalesced atomic scatter: each wave scatters 8 rows, lane-consecutive
    {
#pragma unroll
        for (int r = 0; r < 8; ++r) {
            const int row = wave * 8 + r;
            const int dst = didx[row];
            float* ap = agg + (size_t)dst * 128;
            atomicAdd(&ap[lane], out_lds[row * 132 + lane]);
            atomicAdd(&ap[64 + lane], out_lds[row * 132 + 64 + lane]);
        }
    }
}

// ---------------- Node MLP: cat(agg, grid_nfeat) [256] -> 256 (SiLU) -> 128 (LN) + residual
__global__ __launch_bounds__(512, 4) void node_mlp_kernel(
    const float* __restrict__ agg, const float* __restrict__ gridf,
    const bf16_t* __restrict__ W1T,  // [256][256]
    const float* __restrict__ b1,
    const bf16_t* __restrict__ W2T,  // [128][256]
    const float* __restrict__ b2,
    const float* __restrict__ g, const float* __restrict__ beta,
    float* __restrict__ out) {
    __shared__ bf16_t A_tile[64 * 40];
    __shared__ bf16_t B_tile[256 * 40];
    __shared__ bf16_t h_lds[64 * 264];
    float* out_lds = (float*)h_lds;

    const int tid = threadIdx.x;
    const int wave = tid >> 6, lane = tid & 63;
    const int l15 = lane & 15, lg = lane >> 4;
    const int g0 = blockIdx.x * 64;

    const int n0 = wave * 32;
    f32x4 acc[4][2] = {};
    const int arow = tid >> 3, acq = (tid & 7) * 4;
    const int brow = tid >> 1, bh = tid & 1;

    float4 aR;
    uint4 bR0, bR1;
#define LOAD_A2(kk)                                                              \
    {                                                                            \
        const int kcol = (kk) * 32 + acq;                                        \
        const float* srcp = (kcol < 128)                                         \
                                ? agg + (size_t)(g0 + arow) * 128 + kcol         \
                                : gridf + (size_t)(g0 + arow) * 128 + (kcol - 128); \
        aR = *reinterpret_cast<const float4*>(srcp);                             \
    }
#define LOAD_B2(kk)                                                              \
    {                                                                            \
        const uint4* sp =                                                        \
            reinterpret_cast<const uint4*>(W1T + (size_t)brow * 256 + (kk) * 32 + bh * 16); \
        bR0 = sp[0];                                                             \
        bR1 = sp[1];                                                             \
    }

    LOAD_A2(0);
    LOAD_B2(0);
    for (int kk = 0; kk < 8; ++kk) {
        {
            union { bf16_t h[4]; uint2 u; } pk;
            pk.h[0] = (bf16_t)aR.x; pk.h[1] = (bf16_t)aR.y;
            pk.h[2] = (bf16_t)aR.z; pk.h[3] = (bf16_t)aR.w;
            *reinterpret_cast<uint2*>(&A_tile[arow * 40 + acq]) = pk.u;
            uint4* dp = reinterpret_cast<uint4*>(&B_tile[brow * 40 + bh * 16]);
            dp[0] = bR0; dp[1] = bR1;
        }
        __syncthreads();
        if (kk < 7) {
            LOAD_A2(kk + 1);
            LOAD_B2(kk + 1);
        }
        bf16x8 a[4], b[2];
#pragma unroll
        for (int mt = 0; mt < 4; ++mt)
            a[mt] = *reinterpret_cast<const bf16x8*>(&A_tile[(mt * 16 + l15) * 40 + lg * 8]);
#pragma unroll
        for (int nt = 0; nt < 2; ++nt)
            b[nt] = *reinterpret_cast<const bf16x8*>(&B_tile[(n0 + nt * 16 + l15) * 40 + lg * 8]);
#pragma unroll
        for (int mt = 0; mt < 4; ++mt)
#pragma unroll
            for (int nt = 0; nt < 2; ++nt)
                acc[mt][nt] = MFMA16(a[mt], b[nt], acc[mt][nt]);
        __syncthreads();
    }

#pragma unroll
    for (int mt = 0; mt < 4; ++mt)
#pragma unroll
        for (int nt = 0; nt < 2; ++nt) {
            const int col = n0 + nt * 16 + l15;
            const float bb = b1[col];
#pragma unroll
            for (int i = 0; i < 4; ++i) {
                const int row = mt * 16 + lg * 4 + i;
                const float x = acc[mt][nt][i] + bb;
                const float s = x / (1.f + __expf(-x));
                h_lds[row * 264 + col] = (bf16_t)s;
            }
        }
    __syncthreads();

    f32x4 acc2[4] = {};
    const int n2 = wave * 16;
    const int b2row = tid >> 2, b2q = tid & 3;
    uint4 wR = *reinterpret_cast<const uint4*>(W2T + (size_t)b2row * 256 + b2q * 8);
    for (int kk = 0; kk < 8; ++kk) {
        *reinterpret_cast<uint4*>(&B_tile[b2row * 40 + b2q * 8]) = wR;
        __syncthreads();
        if (kk < 7)
            wR = *reinterpret_cast<const uint4*>(W2T + (size_t)b2row * 256 + (kk + 1) * 32 + b2q * 8);
        bf16x8 a[4], b;
#pragma unroll
        for (int mt = 0; mt < 4; ++mt)
            a[mt] = *reinterpret_cast<const bf16x8*>(&h_lds[(mt * 16 + l15) * 264 + kk * 32 + lg * 8]);
        b = *reinterpret_cast<const bf16x8*>(&B_tile[(n2 + l15) * 40 + lg * 8]);
#pragma unroll
        for (int mt = 0; mt < 4; ++mt)
            acc2[mt] = MFMA16(a[mt], b, acc2[mt]);
        __syncthreads();
    }

#pragma unroll
    for (int mt = 0; mt < 4; ++mt) {
        const int col = n2 + l15;
        const float bb = b2[col];
#pragma unroll
        for (int i = 0; i < 4; ++i) {
            const int row = mt * 16 + lg * 4 + i;
            out_lds[row * 132 + col] = acc2[mt][i] + bb;
        }
    }
    __syncthreads();
    {
        const int row = tid >> 3, j = tid & 7;
        const float* rp = &out_lds[row * 132 + j * 16];
        float v[16];
        float s = 0.f, sq = 0.f;
#pragma unroll
        for (int c = 0; c < 16; ++c) {
            v[c] = rp[c];
            s += v[c];
            sq += v[c] * v[c];
        }
#pragma unroll
        for (int d = 1; d < 8; d <<= 1) {
            s += __shfl_xor(s, d);
            sq += __shfl_xor(sq, d);
        }
        const float mean = s * (1.f / 128.f);
        const float var = sq * (1.f / 128.f) - mean * mean;
        const float rstd = rsqrtf(var + 1e-5f);
        const float* gp = gridf + (size_t)(g0 + row) * 128 + j * 16;
        float* op = out + (size_t)(g0 + row) * 128 + j * 16;
#pragma unroll
        for (int q = 0; q < 4; ++q) {
            float4 gv = *reinterpret_cast<const float4*>(gp + q * 4);
            float4 r;
            r.x = (v[q * 4 + 0] - mean) * rstd * g[j * 16 + q * 4 + 0] + beta[j * 16 + q * 4 + 0] + gv.x;
            r.y = (v[q * 4 + 1] - mean) * rstd * g[j * 16 + q * 4 + 1] + beta[j * 16 + q * 4 + 1] + gv.y;
            r.z = (v[q * 4 + 2] - mean) * rstd * g[j * 16 + q * 4 + 2] + beta[j * 16 + q * 4 + 2] + gv.z;
            r.w = (v[q * 4 + 3] - mean) * rstd * g[j * 16 + q * 4 + 3] + beta[j * 16 + q * 4 + 3] + gv.w;
            *reinterpret_cast<float4*>(op + q * 4) = r;
        }
    }
}

extern "C" void kernel_launch(void* const* d_in, const int* in_sizes, int n_in,
                              void* d_out, int out_size, void* d_ws, size_t ws_size,
                              hipStream_t stream) {
    const float* m2g = (const float*)d_in[0];
    const float* gridf = (const float*)d_in[1];
    const float* meshf = (const float*)d_in[2];
    const int* src_idx = (const int*)d_in[3];
    const int* dst_idx = (const int*)d_in[4];
    const float* eW1 = (const float*)d_in[5];
    const float* eb1 = (const float*)d_in[6];
    const float* eW2 = (const float*)d_in[7];
    const float* eb2 = (const float*)d_in[8];
    const float* eg = (const float*)d_in[9];
    const float* ebeta = (const float*)d_in[10];
    const float* nW1 = (const float*)d_in[11];
    const float* nb1 = (const float*)d_in[12];
    const float* nW2 = (const float*)d_in[13];
    const float* nb2 = (const float*)d_in[14];
    const float* ng = (const float*)d_in[15];
    const float* nbeta = (const float*)d_in[16];
    float* out = (float*)d_out;

    bf16_t* W1eT = (bf16_t*)d_ws;          // [256][384]
    bf16_t* W2eT = W1eT + 256 * 384;       // [128][256]
    bf16_t* W1nT = W2eT + 128 * 256;       // [256][256]
    bf16_t* W2nT = W1nT + 256 * 256;       // [128][256]

    // agg lives in d_out; zero it first (edge kernel atomically accumulates into it)
    hipMemsetAsync(d_out, 0, (size_t)N_GRID * DIM * sizeof(float), stream);

    transpose_to_bf16<<<(384 * 256 + 255) / 256, 256, 0, stream>>>(eW1, W1eT, 384, 256);
    transpose_to_bf16<<<(256 * 128 + 255) / 256, 256, 0, stream>>>(eW2, W2eT, 256, 128);
    transpose_to_bf16<<<(256 * 256 + 255) / 256, 256, 0, stream>>>(nW1, W1nT, 256, 256);
    transpose_to_bf16<<<(256 * 128 + 255) / 256, 256, 0, stream>>>(nW2, W2nT, 256, 128);

    edge_mlp_kernel<<<E_EDGE / 64, 512, 0, stream>>>(m2g, gridf, meshf, src_idx, dst_idx,
                                                     W1eT, eb1, W2eT, eb2, eg, ebeta, out);
    node_mlp_kernel<<<N_GRID / 64, 512, 0, stream>>>(out, gridf, W1nT, nb1, W2nT, nb2,
                                                     ng, nbeta, out);
}